// Round 2
// baseline (127.175 us; speedup 1.0000x reference)
//
#include <hip/hip_runtime.h>

#define B_PATHS 32768
#define N_STEPS 50
#define H 64
#define NS 128             // table points per step; 50*128*4 = 25 KB LDS in sim.
                           // absmax interp-insensitive NS=1024..256 (0.25 flat, tanh-GELU
                           // systematic dominates); NS=128 err ~1e-3 << tolerance.
#define TBL (N_STEPS * NS) // 6400 evals
#define EV 7               // evals per table pass; 2 passes/block covers 512*14 >= 6400
#define NBLK (B_PATHS / 64)// 512 blocks, one wave each; 2 waves/CU -> all co-resident

static __device__ __forceinline__ float gelu_f(float x) {
    // tanh-form GELU: max abs err vs exact-erf ~2e-4
    float x2 = x * x;
    float u  = x * fmaf(x2, 0.044715f * 0.7978845608f, 0.7978845608f);
    float e  = exp2f(u * -2.885390081777927f);   // e^{-2u}
    return x / (1.0f + e);
}

static __device__ __forceinline__ float sigmoid_f(float x) {
    float e = exp2f(x * -1.4426950408889634f);
    return 1.0f / (1.0f + e);
}

// Analytic per-step S envelope (covers 32k-path extremes ~4.2 sigma with 8-sigma bound).
static __device__ __forceinline__ void step_range(int i, float& lo, float& hi) {
    const float sd = 0.2f * 0.14142135623f;     // SIGMA * sqrt(DT)
    float w = fmaf(8.0f * sd, sqrtf((float)i), 0.05f);
    lo = 100.0f * expf(-w);
    hi = 100.0f * expf(w);
}

// Compile-time Y-recurrence weights: Y_50 = a^50*Y0 + sum_i a^(49-i)*0.2*z_i*S_i*dw_i,
// a = 1 + R*DT = 1.001 (dS - rdt*S = 0.2*S*dw exactly).
struct StepW { float w[N_STEPS]; float a50; };
static constexpr StepW make_stepw() {
    StepW t{};
    float apow[N_STEPS];
    float a = 1.0f;
    for (int k = 0; k < N_STEPS; k++) { apow[k] = a; a *= 1.001f; }
    for (int i = 0; i < N_STEPS; i++) t.w[i] = 0.2f * apow[N_STEPS - 1 - i];
    t.a50 = a;
    return t;
}
static constexpr StepW SW = make_stepw();

// Wave64 sum via DPP inclusive scan; lane 63 holds total, broadcast via readlane.
template <int N>
static __device__ __forceinline__ void wave_sumN(float (&v)[N]) {
#define DPP_STAGE(CTRL)                                                                  \
    {                                                                                    \
        float t[N];                                                                      \
        _Pragma("unroll")                                                                \
        for (int e = 0; e < N; e++)                                                      \
            t[e] = __int_as_float(__builtin_amdgcn_update_dpp(                           \
                0, __float_as_int(v[e]), CTRL, 0xf, 0xf, true));                         \
        _Pragma("unroll")                                                                \
        for (int e = 0; e < N; e++) v[e] += t[e];                                        \
    }
    DPP_STAGE(0x111)   // row_shr:1
    DPP_STAGE(0x112)   // row_shr:2
    DPP_STAGE(0x114)   // row_shr:4
    DPP_STAGE(0x118)   // row_shr:8
    DPP_STAGE(0x142)   // row_bcast:15
    DPP_STAGE(0x143)   // row_bcast:31
#undef DPP_STAGE
    #pragma unroll
    for (int e = 0; e < N; e++)
        v[e] = __int_as_float(__builtin_amdgcn_readlane(__float_as_int(v[e]), 63));
}

// Inter-block comms: module globals (no d_ws -> no dependence on ws poison).
// g_arrive is a MONOTONIC counting barrier: never reset; target = next multiple of
// NBLK above this block's ticket. 2^32 % 512 == 0, so wrap-consistent across replays.
__device__ float g_table[TBL];
__device__ unsigned int g_arrive = 0;

// ---------------- fused kernel: table slice -> device barrier -> simulate ----------------
// 512 blocks x 64 threads, all co-resident (LDS 26.75 KB -> 5 blocks/CU cap, need 2).
// Order per block: weight loads, dw loads (latency hides under table compute), envelope,
// table slice (2 passes EV=7, lane=neuron DPP structure), release-arrive EARLY, then
// phase A (independent of table -> covers the spin window), spin, acquire, stage, phase B.
__global__ __launch_bounds__(64, 1) void fused_kernel(
    const float* __restrict__ dw,
    const float* __restrict__ W1, const float* __restrict__ b1,
    const float* __restrict__ g1, const float* __restrict__ be1,
    const float* __restrict__ W2, const float* __restrict__ b2,
    const float* __restrict__ g2, const float* __restrict__ be2,
    const float* __restrict__ W3, const float* __restrict__ b3,
    const float* __restrict__ Y0,
    float* __restrict__ out)
{
    __shared__ float stab[TBL];        // 25 KB: staged zeta table
    __shared__ float shg[EV * H];      // 1.75 KB: layer-2 broadcast buffer

    const int lane = threadIdx.x;
    const int b    = blockIdx.x;
    const int p    = b * 64 + lane;

    const bool has_tbl = (b * (2 * EV) < TBL);   // blocks 0..457 produce table entries

    // ---- weight loads first (oldest in vmcnt queue: table compute waits only on these,
    // ---- leaving the dw loads below still in flight) ----
    float w1a, w1b, bb1, gg1, bbe1, bb2, gg2, bbe2, w3, b3s;
    float w2c[H];
    if (has_tbl) {
        w1a = W1[lane]; w1b = W1[H + lane]; bb1 = b1[lane];
        gg1 = g1[lane]; bbe1 = be1[lane];
        bb2 = b2[lane]; gg2 = g2[lane]; bbe2 = be2[lane];
        w3  = W3[lane]; b3s = b3[0];
        #pragma unroll
        for (int k = 0; k < H; k++) w2c[k] = W2[k * H + lane];   // coalesced column
    }

    // ---- dw preload (first use in phase A; HBM latency hides under table compute) ----
    float dwl[N_STEPS];
    const float2* dw2 = (const float2*)(dw + p * N_STEPS);
    #pragma unroll
    for (int q = 0; q < N_STEPS / 2; q++) {
        float2 v = dw2[q];
        dwl[2 * q]     = v.x;
        dwl[2 * q + 1] = v.y;
    }
    float Y0s = Y0[0];

    // ---- lane-parallel envelope: lane k owns step-k interp constants ----
    const float sd = 0.2f * 0.14142135623f;             // SIGMA * sqrt(DT)
    float wk   = fmaf(8.0f * sd, sqrtf((float)lane), 0.05f);
    float lo_l = 100.0f * expf(-wk);
    float hi_l = 100.0f * expf(wk);
    float sc_l   = (float)(NS - 1) / (hi_l - lo_l);
    float losc_l = lo_l * sc_l;                         // u = S*sc - losc

    // ---- table slice: evals [b*14, b*14+14), two EV=7 passes, lane=neuron ----
    if (has_tbl) {
        #pragma unroll
        for (int pass = 0; pass < 2; pass++) {
            const int e0 = b * (2 * EV) + pass * EV;

            float h[EV], s1[EV];
            #pragma unroll
            for (int e = 0; e < EV; e++) {
                int ee = e0 + e; ee = (ee < TBL - 1) ? ee : (TBL - 1);  // clamp dup-write
                int ii = ee >> 7;                 // step index
                int jj = ee & (NS - 1);           // table point
                float lo, hi;
                step_range(ii, lo, hi);
                float dsg = (hi - lo) * (1.0f / (float)(NS - 1));
                float s   = fmaf(dsg, (float)jj, lo);
                float x1  = (float)ii * 0.02f;    // == t_grid value, bit-exact
                h[e]  = fmaf(s * 0.01f, w1a, fmaf(x1, w1b, bb1));
                s1[e] = h[e];
            }
            wave_sumN<EV>(s1);
            float d[EV], vv[EV];
            #pragma unroll
            for (int e = 0; e < EV; e++) { d[e] = h[e] - s1[e] * (1.0f / H); vv[e] = d[e] * d[e]; }
            wave_sumN<EV>(vv);
            #pragma unroll
            for (int e = 0; e < EV; e++) {
                float rstd = rsqrtf(fmaf(vv[e], 1.0f / H, 1e-5f));
                shg[e * H + lane] = gelu_f(fmaf(d[e] * rstd, gg1, bbe1));
            }
            __syncthreads();                      // single wave: LDS write->read order

            float acc[EV];
            #pragma unroll
            for (int e = 0; e < EV; e++) acc[e] = bb2;
            #pragma unroll
            for (int q = 0; q < H / 4; q++) {
                float4 hv[EV];
                #pragma unroll
                for (int e = 0; e < EV; e++) hv[e] = ((const float4*)(shg + e * H))[q];
                #pragma unroll
                for (int e = 0; e < EV; e++) {
                    acc[e] = fmaf(hv[e].x, w2c[4 * q + 0], acc[e]);
                    acc[e] = fmaf(hv[e].y, w2c[4 * q + 1], acc[e]);
                    acc[e] = fmaf(hv[e].z, w2c[4 * q + 2], acc[e]);
                    acc[e] = fmaf(hv[e].w, w2c[4 * q + 3], acc[e]);
                }
            }
            __syncthreads();                      // shg reused next pass

            float s2[EV];
            #pragma unroll
            for (int e = 0; e < EV; e++) s2[e] = acc[e];
            wave_sumN<EV>(s2);
            float d2[EV], v2[EV];
            #pragma unroll
            for (int e = 0; e < EV; e++) { d2[e] = acc[e] - s2[e] * (1.0f / H); v2[e] = d2[e] * d2[e]; }
            wave_sumN<EV>(v2);
            float zf[EV];
            #pragma unroll
            for (int e = 0; e < EV; e++) {
                float rstd = rsqrtf(fmaf(v2[e], 1.0f / H, 1e-5f));
                zf[e] = gelu_f(fmaf(d2[e] * rstd, gg2, bbe2)) * w3;
            }
            wave_sumN<EV>(zf);

            float zo = sigmoid_f(zf[0] + b3s);
            #pragma unroll
            for (int e = 1; e < EV; e++) {
                float z = sigmoid_f(zf[e] + b3s);
                zo = (lane == e) ? z : zo;
            }
            if (lane < EV) g_table[min(e0 + lane, TBL - 1)] = zo;
        }
    }

    // ---- release-arrive EARLY (before phase A) so other blocks' spins end asap ----
    __threadfence();                               // publish g_table (agent-scope release)
    unsigned target = 0;
    if (lane == 0) {
        unsigned old = atomicAdd(&g_arrive, 1u);   // device-scope
        target = old - (old % NBLK) + NBLK;        // next multiple of NBLK
    }

    // ---- phase A: S product chain + interp coords + weighted c-terms (no table dep) ----
    float u[N_STEPS], g[N_STEPS];
    float S = 100.0f;
    #pragma unroll
    for (int i = 0; i < N_STEPS; i++) {
        float sc   = __int_as_float(__builtin_amdgcn_readlane(__float_as_int(sc_l),   i));
        float losc = __int_as_float(__builtin_amdgcn_readlane(__float_as_int(losc_l), i));
        float uu = fmaf(S, sc, -losc);
        u[i] = fminf(fmaxf(uu, 0.0f), (float)(NS - 1));
        float v = dwl[i];
        g[i] = S * (v * SW.w[i]);                 // Y-weight folded at build time
        S = S * fmaf(0.2f, v, 1.001f);            // S_{i+1} = S_i*(1 + rdt + 0.2*dw)
    }

    // ---- spin until all NBLK blocks have arrived (co-residency guaranteed) ----
    if (lane == 0) {
        while (__hip_atomic_load(&g_arrive, __ATOMIC_RELAXED, __HIP_MEMORY_SCOPE_AGENT) < target)
            __builtin_amdgcn_s_sleep(2);
    }
    __syncthreads();
    __threadfence();                               // acquire: fresh view of g_table

    // ---- stage table -> LDS (25 float4/lane, L2-hot: all blocks read same 25 KB) ----
    const float4* tg = (const float4*)g_table;
    float4* ts = (float4*)stab;
    #pragma unroll
    for (int q = 0; q < (TBL / 4) / 64; q++)       // 25
        ts[q * 64 + lane] = tg[q * 64 + lane];
    __syncthreads();

    // ---- phase B: 50 independent gather+fma terms, 4 rotating accumulators ----
    float acc[4] = {0.0f, 0.0f, 0.0f, 0.0f};
    #pragma unroll
    for (int i = 0; i < N_STEPS; i++) {
        float uu = u[i];
        int jj = (int)uu;
        jj = min(jj, NS - 2);
        float f = uu - (float)jj;
        const float* row = stab + i * NS;
        float z0 = row[jj];
        float z1 = row[jj + 1];
        float z = fmaf(f, z1 - z0, z0);
        acc[i & 3] = fmaf(z, g[i], acc[i & 3]);
    }
    float Y = fmaf(SW.a50, Y0s, (acc[0] + acc[1]) + (acc[2] + acc[3]));
    out[p] = Y;
    out[B_PATHS + p] = S;
}

extern "C" void kernel_launch(void* const* d_in, const int* in_sizes, int n_in,
                              void* d_out, int out_size, void* d_ws, size_t ws_size,
                              hipStream_t stream)
{
    const float* dw  = (const float*)d_in[0];
    const float* W1  = (const float*)d_in[2];
    const float* b1  = (const float*)d_in[3];
    const float* g1  = (const float*)d_in[4];
    const float* be1 = (const float*)d_in[5];
    const float* W2  = (const float*)d_in[6];
    const float* b2  = (const float*)d_in[7];
    const float* g2  = (const float*)d_in[8];
    const float* be2 = (const float*)d_in[9];
    const float* W3  = (const float*)d_in[10];
    const float* b3  = (const float*)d_in[11];
    const float* Y0  = (const float*)d_in[12];
    float* out = (float*)d_out;
    (void)d_ws; (void)ws_size;                    // workspace unused: table in __device__

    fused_kernel<<<NBLK, 64, 0, stream>>>(
        dw, W1, b1, g1, be1, W2, b2, g2, be2, W3, b3, Y0, out);
}

// Round 3
// 90.829 us; speedup vs baseline: 1.4002x; 1.4002x over previous
//
#include <hip/hip_runtime.h>

#define B_PATHS 32768
#define N_STEPS 50
#define H 64
#define NS 32              // table points per step; 50*32*4 = 6.4 KB LDS in sim.
                           // linear-interp err ~ (1/NS)^2: NS=128 was ~1e-3, NS=32 ~1.6e-2
                           // — still 15x below the 0.25 tanh-GELU systematic floor
                           // (absmax 0.5 vs threshold ~4.9). Cuts table_kernel work 4x.
#define TBL (N_STEPS * NS) // 1600 evals
#define EV 4               // evals per wave: VGPR ~100, no scratch spills (r7 lesson)

static __device__ __forceinline__ float gelu_f(float x) {
    // tanh-form GELU: max abs err vs exact-erf ~2e-4
    float x2 = x * x;
    float u  = x * fmaf(x2, 0.044715f * 0.7978845608f, 0.7978845608f);
    float e  = exp2f(u * -2.885390081777927f);   // e^{-2u}
    return x / (1.0f + e);
}

static __device__ __forceinline__ float sigmoid_f(float x) {
    float e = exp2f(x * -1.4426950408889634f);
    return 1.0f / (1.0f + e);
}

// Analytic per-step S envelope (covers 32k-path extremes ~4.2 sigma with 8-sigma bound).
static __device__ __forceinline__ void step_range(int i, float& lo, float& hi) {
    const float sd = 0.2f * 0.14142135623f;     // SIGMA * sqrt(DT)
    float w = fmaf(8.0f * sd, sqrtf((float)i), 0.05f);
    lo = 100.0f * expf(-w);
    hi = 100.0f * expf(w);
}

// Compile-time Y-recurrence weights.
// Y_{i+1} = a*Y_i + z_i*(dS_i - rdt*S_i), a = 1 + R*DT = 1.001,
// and dS - rdt*S = SIGMA*S*dw exactly, so
// Y_50 = a^50 * Y0 + sum_i a^(49-i) * 0.2 * z_i * S_i * dw_i.
struct StepW { float w[N_STEPS]; float a50; };
static constexpr StepW make_stepw() {
    StepW t{};
    float apow[N_STEPS];
    float a = 1.0f;
    for (int k = 0; k < N_STEPS; k++) { apow[k] = a; a *= 1.001f; }  // apow[k] = a^k
    for (int i = 0; i < N_STEPS; i++) t.w[i] = 0.2f * apow[N_STEPS - 1 - i];
    t.a50 = a;                                                        // a^50
    return t;
}
static constexpr StepW SW = make_stepw();

// Wave64 sum via DPP inclusive scan (VALU pipe) — AMDGPUAtomicOptimizer sequence:
// row_shr:1,2,4,8 then row_bcast:15, row_bcast:31; lane 63 holds the total.
// old=0 + bound_ctrl=1: invalid-source lanes read the additive identity.
template <int N>
static __device__ __forceinline__ void wave_sumN(float (&v)[N]) {
#define DPP_STAGE(CTRL)                                                                  \
    {                                                                                    \
        float t[N];                                                                      \
        _Pragma("unroll")                                                                \
        for (int e = 0; e < N; e++)                                                      \
            t[e] = __int_as_float(__builtin_amdgcn_update_dpp(                           \
                0, __float_as_int(v[e]), CTRL, 0xf, 0xf, true));                         \
        _Pragma("unroll")                                                                \
        for (int e = 0; e < N; e++) v[e] += t[e];                                        \
    }
    DPP_STAGE(0x111)   // row_shr:1
    DPP_STAGE(0x112)   // row_shr:2
    DPP_STAGE(0x114)   // row_shr:4
    DPP_STAGE(0x118)   // row_shr:8
    DPP_STAGE(0x142)   // row_bcast:15
    DPP_STAGE(0x143)   // row_bcast:31
#undef DPP_STAGE
    #pragma unroll
    for (int e = 0; e < N; e++)
        v[e] = __int_as_float(__builtin_amdgcn_readlane(__float_as_int(v[e]), 63));
}

// ---------------- pass 1: tabulate zeta_i(s), weight-stationary + DPP ----------------
// Lane n owns neuron n; W2 column n in 64 VGPRs (loaded once per wave, L2-hot after
// the first blocks). LN reductions on the VALU pipe (DPP). Layer-2 hg broadcast via
// LDS: 1 ds_write + 16 wave-uniform ds_read_b128 per eval (same-address broadcast).
// 50*(32/4) = 400 blocks of one wave (was 1600 at NS=128 — 4x less DPP work).
__global__ __launch_bounds__(64) void table_kernel(
    const float* __restrict__ W1, const float* __restrict__ b1,
    const float* __restrict__ g1, const float* __restrict__ be1,
    const float* __restrict__ W2, const float* __restrict__ b2,
    const float* __restrict__ g2, const float* __restrict__ be2,
    const float* __restrict__ W3, const float* __restrict__ b3,
    float* __restrict__ table)
{
    __shared__ float shg[EV * H];        // 1 KB

    int lane = threadIdx.x;
    int i  = blockIdx.x >> 3;            // step index (NS/EV = 8 blocks per step)
    int j0 = (blockIdx.x & 7) * EV;      // first table point of this wave

    float w1a = W1[lane], w1b = W1[H + lane], bb1 = b1[lane];
    float gg1 = g1[lane], bbe1 = be1[lane];
    float bb2 = b2[lane], gg2 = g2[lane], bbe2 = be2[lane];
    float w3  = W3[lane];
    float b3s = b3[0];

    float w2c[H];                        // W2 column `lane`: coalesced, once
    #pragma unroll
    for (int k = 0; k < H; k++) w2c[k] = W2[k * H + lane];

    float lo, hi;
    step_range(i, lo, hi);
    float x1  = (float)i * 0.02f;        // == t_grid row value, bit-exact
    float dsg = (hi - lo) * (1.0f / (float)(NS - 1));

    // ---- layer 1 + LN1 + gelu ----
    float h[EV], s1[EV];
    #pragma unroll
    for (int e = 0; e < EV; e++) {
        float s  = fmaf(dsg, (float)(j0 + e), lo);
        h[e] = fmaf(s * 0.01f, w1a, fmaf(x1, w1b, bb1));
        s1[e] = h[e];
    }
    wave_sumN<EV>(s1);
    float d[EV], vv[EV];
    #pragma unroll
    for (int e = 0; e < EV; e++) { d[e] = h[e] - s1[e] * (1.0f / H); vv[e] = d[e] * d[e]; }
    wave_sumN<EV>(vv);
    #pragma unroll
    for (int e = 0; e < EV; e++) {
        float rstd = rsqrtf(fmaf(vv[e], 1.0f / H, 1e-5f));
        shg[e * H + lane] = gelu_f(fmaf(d[e] * rstd, gg1, bbe1));
    }
    __syncthreads();                     // single wave: just orders LDS write->read

    // ---- layer 2: acc[e] = sum_k hg[e][k] * w2c[k], hg via wave-uniform b128 reads ----
    float acc[EV];
    #pragma unroll
    for (int e = 0; e < EV; e++) acc[e] = bb2;
    #pragma unroll
    for (int q = 0; q < H / 4; q++) {
        float4 hv[EV];
        #pragma unroll
        for (int e = 0; e < EV; e++) hv[e] = ((const float4*)(shg + e * H))[q];
        #pragma unroll
        for (int e = 0; e < EV; e++) {
            acc[e] = fmaf(hv[e].x, w2c[4 * q + 0], acc[e]);
            acc[e] = fmaf(hv[e].y, w2c[4 * q + 1], acc[e]);
            acc[e] = fmaf(hv[e].z, w2c[4 * q + 2], acc[e]);
            acc[e] = fmaf(hv[e].w, w2c[4 * q + 3], acc[e]);
        }
    }

    // ---- LN2 + gelu + layer 3 + sigmoid ----
    float s2[EV];
    #pragma unroll
    for (int e = 0; e < EV; e++) s2[e] = acc[e];
    wave_sumN<EV>(s2);
    float d2[EV], v2[EV];
    #pragma unroll
    for (int e = 0; e < EV; e++) { d2[e] = acc[e] - s2[e] * (1.0f / H); v2[e] = d2[e] * d2[e]; }
    wave_sumN<EV>(v2);
    float zf[EV];
    #pragma unroll
    for (int e = 0; e < EV; e++) {
        float rstd = rsqrtf(fmaf(v2[e], 1.0f / H, 1e-5f));
        zf[e] = gelu_f(fmaf(d2[e] * rstd, gg2, bbe2)) * w3;
    }
    wave_sumN<EV>(zf);

    // lane e stores eval e (select chain avoids runtime-indexed register array)
    float zo = sigmoid_f(zf[0] + b3s);
    #pragma unroll
    for (int e = 1; e < EV; e++) {
        float z = sigmoid_f(zf[e] + b3s);
        zo = (lane == e) ? z : zo;
    }
    if (lane < EV) table[i * NS + j0 + lane] = zo;
}

// ---------------- pass 2: simulate paths, table gathered from LDS ----------------
// 512 blocks x 64 threads. Staging issued first; envelope computed lane-parallel
// (lane k owns step k, broadcast later via v_readlane with compile-time indices —
// no barrier, so staging latency still hides under phase A).
// Y-chain flattened to a weighted sum (closed form, SW weights): phase B has NO
// serial recurrence — 50 independent gather+fma terms into 4 accumulators.
__global__ __launch_bounds__(64) void sim_kernel(const float* __restrict__ dw,
                                                 const float* __restrict__ table,
                                                 const float* __restrict__ Y0,
                                                 float* __restrict__ out)
{
    __shared__ float stab[TBL];            // 6.4 KB

    int lane = threadIdx.x;

    // issue staging (400 float4 total; 7 per lane, last iter predicated);
    // latency hides under dw loads + envelope + phase A below
    const float4* tg = (const float4*)table;
    float4* ts = (float4*)stab;
    #pragma unroll
    for (int q = 0; q < (TBL / 4 + 63) / 64; q++) {   // 7 iters, 400 total
        int idx = q * 64 + lane;
        if (idx < TBL / 4) ts[idx] = tg[idx];
    }

    // lane-parallel envelope: lane k computes step-k interp constants (1 sqrt +
    // 2 exp + 1 div per THREAD total). Lanes >= 50 unused.
    const float sd = 0.2f * 0.14142135623f;             // SIGMA * sqrt(DT)
    float wk   = fmaf(8.0f * sd, sqrtf((float)lane), 0.05f);
    float lo_l = 100.0f * expf(-wk);
    float hi_l = 100.0f * expf(wk);
    float sc_l   = (float)(NS - 1) / (hi_l - lo_l);     // scale
    float losc_l = lo_l * sc_l;                         // lo*scale (u = S*sc - losc)

    int p = blockIdx.x * 64 + lane;
    const float nsm1 = (float)(NS - 1);

    float dwl[N_STEPS];
    const float2* dw2 = (const float2*)(dw + p * N_STEPS);
    #pragma unroll
    for (int q = 0; q < N_STEPS / 2; q++) {
        float2 v = dw2[q];
        dwl[2 * q]     = v.x;
        dwl[2 * q + 1] = v.y;
    }

    // phase A: S product chain (only serial chain) + interp coords + weighted
    // c-term precursors g[i] = S_i * dw_i * (0.2 * a^(49-i))
    float u[N_STEPS], g[N_STEPS];
    float S = 100.0f;
    #pragma unroll
    for (int i = 0; i < N_STEPS; i++) {
        float sc   = __int_as_float(__builtin_amdgcn_readlane(__float_as_int(sc_l),   i));
        float losc = __int_as_float(__builtin_amdgcn_readlane(__float_as_int(losc_l), i));
        float uu = fmaf(S, sc, -losc);
        u[i] = fminf(fmaxf(uu, 0.0f), nsm1);
        float v = dwl[i];
        g[i] = S * (v * SW.w[i]);                 // weight folded at build time
        S = S * fmaf(0.2f, v, 1.001f);            // S_{i+1} = S_i*(1 + rdt + 0.2*dw)
    }

    __syncthreads();                     // staging complete; table needed from here

    // phase B: independent gather+fma terms, 4 rotating accumulators (pure ILP)
    float acc[4] = {0.0f, 0.0f, 0.0f, 0.0f};
    #pragma unroll
    for (int i = 0; i < N_STEPS; i++) {
        float uu = u[i];
        int jj = (int)uu;
        jj = min(jj, NS - 2);
        float f = uu - (float)jj;
        const float* row = stab + i * NS;
        float z0 = row[jj];
        float z1 = row[jj + 1];
        float z = fmaf(f, z1 - z0, z0);
        acc[i & 3] = fmaf(z, g[i], acc[i & 3]);   // i&3 is unroll-constant: stays in regs
    }
    float Y = fmaf(SW.a50, Y0[0], (acc[0] + acc[1]) + (acc[2] + acc[3]));
    out[p] = Y;
    out[B_PATHS + p] = S;
}

extern "C" void kernel_launch(void* const* d_in, const int* in_sizes, int n_in,
                              void* d_out, int out_size, void* d_ws, size_t ws_size,
                              hipStream_t stream)
{
    const float* dw  = (const float*)d_in[0];
    const float* W1  = (const float*)d_in[2];
    const float* b1  = (const float*)d_in[3];
    const float* g1  = (const float*)d_in[4];
    const float* be1 = (const float*)d_in[5];
    const float* W2  = (const float*)d_in[6];
    const float* b2  = (const float*)d_in[7];
    const float* g2  = (const float*)d_in[8];
    const float* be2 = (const float*)d_in[9];
    const float* W3  = (const float*)d_in[10];
    const float* b3  = (const float*)d_in[11];
    const float* Y0  = (const float*)d_in[12];
    float* out   = (float*)d_out;
    float* table = (float*)d_ws;           // 6.4 KB used

    table_kernel<<<N_STEPS * (NS / EV), 64, 0, stream>>>(
        W1, b1, g1, be1, W2, b2, g2, be2, W3, b3, table);
    sim_kernel<<<B_PATHS / 64, 64, 0, stream>>>(dw, table, Y0, out);
}